// Round 5
// baseline (179.736 us; speedup 1.0000x reference)
//
#include <hip/hip_runtime.h>
#include <hip/hip_cooperative_groups.h>
#include <math.h>

namespace cg = cooperative_groups;

#define NSEG 2048
#define ROW 65
#define MMAX 4226          // max flat coef entries (M+1), M <= 64*65+64 = 4224
#define TCAP 4240          // flat knot array capacity incl window-read padding
#define NC 4096            // grid cells
#define GLO (-9.0f)
#define GHI (9.0f)
#define DXF ((GHI - GLO) / NC)
#define INVDX (NC / (GHI - GLO))
#define PPT 8
#define CAP 64             // per-block segment-aggregation slots
#define SCALEF 1073741824.0f  // 2^30 (exact exponent shift in fp32)
#define SCALE  1073741824.0

// ---- k_pre_ab: zero accumulators + per-interval crossing tables ----
// 65 blocks x 64 threads; each block redundantly sorts the 64 inner-relu
// breakpoints (cheap shfl rank-sort), then handles coarse interval k=blockIdx.
__global__ __launch_bounds__(64) void k_pre_ab(
    const float* __restrict__ W1, const float* __restrict__ b1,
    const float* __restrict__ W2, const float* __restrict__ b2,
    const float* __restrict__ W3,
    unsigned long long* __restrict__ pooled, int* __restrict__ counts,
    float* __restrict__ bpg, float* __restrict__ knots, float2* __restrict__ coef,
    int* __restrict__ nvalid)
{
    __shared__ float bps[64];
    __shared__ float w2s[64 * 65];   // padded: row stride 65 kills bank conflicts
    const int lane = threadIdx.x;
    const int k = blockIdx.x;

    // zero the global accumulators (spread across the 65 blocks)
    for (int i = k * 64 + lane; i < NSEG; i += 65 * 64) { pooled[i] = 0ull; counts[i] = 0; }

    // breakpoints: t_j = -b1/W1 (W1==0 -> sentinel), stable shfl rank-sort
    float w1l = W1[lane], b1l = b1[lane];
    float t = (w1l != 0.0f) ? (-b1l / w1l) : 3.0e38f;
    int r = 0;
    for (int l = 0; l < 64; ++l) {
        float o = __shfl(t, l);
        r += (o < t) || (o == t && l < lane);
    }
    bps[r] = t;

    // stage W2 into padded LDS (coalesced global reads)
    for (int i = lane; i < 4096; i += 64)
        w2s[(i >> 6) * 65 + (i & 63)] = W2[i];
    __syncthreads();
    if (k == 0) bpg[lane] = bps[lane];

    // affine coeffs of z_i (i = lane) on interval k: z = a*x + b
    float lof = (k == 0) ? (bps[0] - 1.0f) : bps[k - 1];
    float hif = (k == 64) ? (bps[63] + 1.0f) : bps[k];
    float xm = lof + 0.5f * (hif - lof);
    float a = 0.0f, b = b2[lane];
    for (int j = 0; j < 64; ++j) {
        float w1 = W1[j];
        if (w1 * xm + b1[j] > 0.0f) {
            float w2 = w2s[lane * 65 + j];
            a += w2 * w1;
            b += w2 * b1[j];
        }
    }

    // outer-relu crossing of z_i inside the open interval
    float w3 = W3[lane];
    float lo = (k == 0) ? -INFINITY : bps[k - 1];
    float hi = (k == 64) ? INFINITY : bps[k];
    float c = INFINITY, da = 0.0f, db = 0.0f;
    if (a != 0.0f) {
        float cc = -b / a;
        if (cc > lo && cc < hi) {
            float s = (a > 0.0f) ? 1.0f : -1.0f;
            c = cc; da = s * w3 * a; db = s * w3 * b;
        }
    }
    // active set just right of left edge -> (a0,b0)
    bool act;
    if (k == 0) act = (a < 0.0f) || (a == 0.0f && b > 0.0f);
    else { float v = a * lo + b; act = (v > 0.0f) || (v == 0.0f && a > 0.0f); }
    float a0 = act ? w3 * a : 0.0f;
    float b0 = act ? w3 * b : 0.0f;
    for (int d = 32; d; d >>= 1) { a0 += __shfl_xor(a0, d); b0 += __shfl_xor(b0, d); }

    // stable rank sort of crossings (inf = invalid go last)
    int rank = 0;
    for (int l = 0; l < 64; ++l) {
        float o = __shfl(c, l);
        rank += (o < c) || (o == c && l < lane);
    }
    int src = 0;
    for (int l = 0; l < 64; ++l) {
        int rr = __shfl(rank, l);
        if (rr == lane) src = l;
    }
    float cs  = __shfl(c, src);
    float das = __shfl(da, src);
    float dbs = __shfl(db, src);
    for (int d = 1; d < 64; d <<= 1) {  // inclusive scan in sorted order
        float ta = __shfl_up(das, d);
        float tb = __shfl_up(dbs, d);
        if (lane >= d) { das += ta; dbs += tb; }
    }
    knots[k * ROW + lane] = cs;
    if (lane == 0) coef[k * ROW] = make_float2(a0, b0);
    coef[k * ROW + lane + 1] = make_float2(a0 + das, b0 + dbs);

    unsigned long long vm = __ballot(isfinite(c));
    if (lane == 0) nvalid[k] = (int)__popcll(vm);
}

// ---- k_pre_c: flatten (k,j) tables into one sorted knot array + grid (1 block) ----
__global__ __launch_bounds__(256) void k_pre_c(
    const float* __restrict__ bpg, float* __restrict__ knots,
    float2* __restrict__ coef, const int* __restrict__ nvalid,
    unsigned short* __restrict__ baseg)
{
    __shared__ float  T_s[TCAP];
    __shared__ float2 C_s[MMAX];
    __shared__ int off[66];
    const int tid = threadIdx.x;
    if (tid == 0) {
        int o = 0;
        for (int k = 0; k < 65; ++k) { off[k] = o; o += nvalid[k] + 1; }
        off[65] = o;  // = M + 1 coef entries; M = o - 1 knots
    }
    __syncthreads();
    const int M = off[65] - 1;

    for (int p = tid; p < 65 * ROW; p += 256) {
        int k = p / ROW, j = p - k * ROW;
        int nv = nvalid[k];
        int o = off[k];
        if (j < nv) T_s[o + j] = knots[k * ROW + j];
        else if (j == nv && k < 64) T_s[o + j] = bpg[k];
        if (j <= nv) C_s[o + j] = coef[k * ROW + j];
    }
    float2 lastC = coef[64 * ROW + nvalid[64]];
    __syncthreads();
    for (int i = M + tid; i < TCAP; i += 256) T_s[i] = INFINITY;     // knot sentinels
    for (int i = M + 1 + tid; i < MMAX; i += 256) C_s[i] = lastC;    // coef pad
    __syncthreads();

    for (int i = tid; i < TCAP; i += 256) knots[i] = T_s[i];
    for (int i = tid; i < MMAX; i += 256) coef[i] = C_s[i];
    for (int c = tid; c < NC; c += 256) {
        float left = GLO + c * DXF;
        int lo = 0, hi = M;  // lower bound: #{T <= left}
        while (lo < hi) { int mid = (lo + hi) >> 1; if (T_s[mid] <= left) lo = mid + 1; else hi = mid; }
        baseg[c] = (unsigned short)lo;
    }
}

// ---- k_fused: eval + segment pooling + grid.sync + weight broadcast ----
__global__ __launch_bounds__(256, 4) void k_fused(
    const float* __restrict__ x, const int* __restrict__ batch,
    const float* __restrict__ Tf, const float2* __restrict__ Cf,
    const unsigned short* __restrict__ baseg,
    unsigned long long* __restrict__ pooled, int* __restrict__ counts,
    const float* __restrict__ b3, float* __restrict__ out, int n)
{
    __shared__ __align__(16) float T_s[TCAP];        // 16960 B
    __shared__ unsigned short base_s[NC];            //  8192 B
    __shared__ unsigned long long aggP[CAP];         //   512 B
    __shared__ int aggC[CAP];                        //   256 B
    __shared__ int segFirst_s;
    const int tid = threadIdx.x;
    const float b3v = b3[0];

    for (int i = tid; i < TCAP / 4; i += 256)
        ((float4*)T_s)[i] = ((const float4*)Tf)[i];
    for (int i = tid; i < NC / 2; i += 256)
        ((unsigned int*)base_s)[i] = ((const unsigned int*)baseg)[i];
    if (tid < CAP) { aggP[tid] = 0ull; aggC[tid] = 0; }

    long long base = ((long long)blockIdx.x * 256 + tid) * PPT;
    const bool active = base < n;   // n % PPT == 0 -> active threads do full vectors

    float xs[PPT]; int ss[PPT];
    if (active) {
        const float4* xp = (const float4*)(x + base);
        const int4*   bp = (const int4*)(batch + base);
#pragma unroll
        for (int v = 0; v < PPT / 4; ++v) {
            float4 xv4 = xp[v]; int4 s4 = bp[v];
            xs[4 * v + 0] = xv4.x; xs[4 * v + 1] = xv4.y; xs[4 * v + 2] = xv4.z; xs[4 * v + 3] = xv4.w;
            ss[4 * v + 0] = s4.x;  ss[4 * v + 1] = s4.y;  ss[4 * v + 2] = s4.z;  ss[4 * v + 3] = s4.w;
        }
        if (tid == 0) segFirst_s = ss[0];
    }
    __syncthreads();
    const int segFirst = segFirst_s;

    // ---- phase 1: eval g(x), pool into segments ----
    if (active) {
        int curSeg = -1; long long acc = 0; int cnt = 0;
#pragma unroll
        for (int p = 0; p < PPT; ++p) {
            float xv = xs[p];
            int m;
            if (xv >= GLO) {
                int c = (int)((xv - GLO) * INVDX);
                c = c < NC - 1 ? c : NC - 1;
                if (c > 0 && GLO + c * DXF > xv) --c;  // fp rounding guard
                int b0i = base_s[c];
                int a0 = b0i & ~3;
                const float4* tw = (const float4*)(T_s + a0);
                float4 t0 = tw[0], t1 = tw[1], t2 = tw[2];
                int cw = (t0.x <= xv) + (t0.y <= xv) + (t0.z <= xv) + (t0.w <= xv)
                       + (t1.x <= xv) + (t1.y <= xv) + (t1.z <= xv) + (t1.w <= xv)
                       + (t2.x <= xv) + (t2.y <= xv) + (t2.z <= xv) + (t2.w <= xv);
                m = a0 + cw;
                if (cw == 12) { while (T_s[m] <= xv) ++m; }  // ~never taken
            } else m = 0;
            float2 ab = Cf[m];                 // 34 KB table, L1/L2 resident
            float g = fmaf(ab.x, xv, ab.y);
            long long q = (long long)(g * SCALEF);
            int s = ss[p];
            if (s != curSeg) {
                if (cnt) {
                    int idx = curSeg - segFirst;
                    if (idx < CAP) {
                        atomicAdd(&aggP[idx], (unsigned long long)acc);
                        atomicAdd(&aggC[idx], cnt);
                    } else {
                        atomicAdd(&pooled[curSeg], (unsigned long long)acc);
                        atomicAdd(&counts[curSeg], cnt);
                    }
                }
                curSeg = s; acc = q; cnt = 1;
            } else { acc += q; ++cnt; }
        }
        if (cnt) {
            int idx = curSeg - segFirst;
            if (idx < CAP) {
                atomicAdd(&aggP[idx], (unsigned long long)acc);
                atomicAdd(&aggC[idx], cnt);
            } else {
                atomicAdd(&pooled[curSeg], (unsigned long long)acc);
                atomicAdd(&counts[curSeg], cnt);
            }
        }
    }
    __syncthreads();
    if (tid < CAP) {
        int c = aggC[tid];
        if (c) {
            atomicAdd(&pooled[segFirst + tid], aggP[tid]);
            atomicAdd(&counts[segFirst + tid], c);
        }
    }
    __threadfence();           // make atomics globally visible before grid sync
    cg::this_grid().sync();

    // ---- phase 2: per-point weight broadcast (x/batch already in registers) ----
    if (active) {
        float ov[PPT];
        int lastSeg = -1; float w = 0.0f;
#pragma unroll
        for (int p = 0; p < PPT; ++p) {
            int s = ss[p];
            if (s != lastSeg) {
                lastSeg = s;
                unsigned long long pv = __hip_atomic_load(&pooled[s], __ATOMIC_RELAXED,
                                                          __HIP_MEMORY_SCOPE_AGENT);
                int cv = __hip_atomic_load(&counts[s], __ATOMIC_RELAXED,
                                           __HIP_MEMORY_SCOPE_AGENT);
                double mean = ((double)(long long)pv / SCALE) / (double)cv;
                w = fmaxf((float)(mean + (double)b3v), 0.0f);
            }
            ov[p] = w;
        }
        float4* op = (float4*)(out + base);
        op[0] = make_float4(ov[0], ov[1], ov[2], ov[3]);
        op[1] = make_float4(ov[4], ov[5], ov[6], ov[7]);
    }
}

extern "C" void kernel_launch(void* const* d_in, const int* in_sizes, int n_in,
                              void* d_out, int out_size, void* d_ws, size_t ws_size,
                              hipStream_t stream)
{
    const float* x   = (const float*)d_in[0];
    const int* batch = (const int*)d_in[1];
    const float* W1 = (const float*)d_in[2];
    const float* b1 = (const float*)d_in[3];
    const float* W2 = (const float*)d_in[4];
    const float* b2 = (const float*)d_in[5];
    const float* W3 = (const float*)d_in[6];
    const float* b3 = (const float*)d_in[7];
    float* out = (float*)d_out;
    int n = in_sizes[0];

    char* ws = (char*)d_ws;
    unsigned long long* pooled = (unsigned long long*)ws;   // 16384
    int*    counts  = (int*)(ws + 16384);                   // 8192
    float*  bpg     = (float*)(ws + 24576);                 // 256
    int*    nvalid  = (int*)(ws + 24832);                   // 272
    float*  knots   = (float*)(ws + 25104);                 // 65*65 then flat T[TCAP]: 16960
    float2* coef    = (float2*)(ws + 42064);                // 65*65 then flat C[MMAX]: 33808
    unsigned short* baseg = (unsigned short*)(ws + 75872);  // 8192 -> total ~84 KB

    k_pre_ab<<<65, 64, 0, stream>>>(W1, b1, W2, b2, W3, pooled, counts,
                                    bpg, knots, coef, nvalid);
    k_pre_c<<<1, 256, 0, stream>>>(bpg, knots, coef, nvalid, baseg);

    const int eblocks = (int)((n + 256LL * PPT - 1) / (256LL * PPT));
    void* args[] = {(void*)&x, (void*)&batch, (void*)&knots, (void*)&coef,
                    (void*)&baseg, (void*)&pooled, (void*)&counts,
                    (void*)&b3, (void*)&out, (void*)&n};
    hipLaunchCooperativeKernel((const void*)k_fused, dim3(eblocks), dim3(256),
                               args, 0, stream);
}

// Round 6
// 56.710 us; speedup vs baseline: 3.1694x; 3.1694x over previous
//
#include <hip/hip_runtime.h>
#include <math.h>

#define NSEG 2048
#define ROW 65
#define MMAX 4226          // max flat coef entries (M+1), M <= 64*65+64 = 4224
#define TCAP 4240          // flat knot array capacity incl window-read padding
#define NC 4096            // grid cells
#define GLO (-9.0f)
#define GHI (9.0f)
#define DXF ((GHI - GLO) / NC)
#define INVDX (NC / (GHI - GLO))
#define PPT 8
#define CAP 64             // per-block segment-aggregation slots
#define SCALEF 1073741824.0f  // 2^30 (exact exponent shift in fp32)
#define SCALE  1073741824.0

// ---- k_pre_ab: zero accumulators + per-interval crossing tables ----
// 65 blocks x 64 threads; each block redundantly sorts the 64 inner-relu
// breakpoints (cheap shfl rank-sort), then handles coarse interval k=blockIdx.
__global__ __launch_bounds__(64) void k_pre_ab(
    const float* __restrict__ W1, const float* __restrict__ b1,
    const float* __restrict__ W2, const float* __restrict__ b2,
    const float* __restrict__ W3,
    unsigned long long* __restrict__ pooled, int* __restrict__ counts,
    float* __restrict__ bpg, float* __restrict__ knots, float2* __restrict__ coef,
    int* __restrict__ nvalid)
{
    __shared__ float bps[64];
    __shared__ float w2s[64 * 65];   // padded: row stride 65 kills bank conflicts
    const int lane = threadIdx.x;
    const int k = blockIdx.x;

    // zero the global accumulators (spread across the 65 blocks)
    for (int i = k * 64 + lane; i < NSEG; i += 65 * 64) { pooled[i] = 0ull; counts[i] = 0; }

    // breakpoints: t_j = -b1/W1 (W1==0 -> sentinel), stable shfl rank-sort
    float w1l = W1[lane], b1l = b1[lane];
    float t = (w1l != 0.0f) ? (-b1l / w1l) : 3.0e38f;
    int r = 0;
    for (int l = 0; l < 64; ++l) {
        float o = __shfl(t, l);
        r += (o < t) || (o == t && l < lane);
    }
    bps[r] = t;

    // stage W2 into padded LDS (coalesced global reads)
    for (int i = lane; i < 4096; i += 64)
        w2s[(i >> 6) * 65 + (i & 63)] = W2[i];
    __syncthreads();
    if (k == 0) bpg[lane] = bps[lane];

    // affine coeffs of z_i (i = lane) on interval k: z = a*x + b
    float lof = (k == 0) ? (bps[0] - 1.0f) : bps[k - 1];
    float hif = (k == 64) ? (bps[63] + 1.0f) : bps[k];
    float xm = lof + 0.5f * (hif - lof);
    float a = 0.0f, b = b2[lane];
    for (int j = 0; j < 64; ++j) {
        float w1 = W1[j];
        if (w1 * xm + b1[j] > 0.0f) {
            float w2 = w2s[lane * 65 + j];
            a += w2 * w1;
            b += w2 * b1[j];
        }
    }

    // outer-relu crossing of z_i inside the open interval
    float w3 = W3[lane];
    float lo = (k == 0) ? -INFINITY : bps[k - 1];
    float hi = (k == 64) ? INFINITY : bps[k];
    float c = INFINITY, da = 0.0f, db = 0.0f;
    if (a != 0.0f) {
        float cc = -b / a;
        if (cc > lo && cc < hi) {
            float s = (a > 0.0f) ? 1.0f : -1.0f;
            c = cc; da = s * w3 * a; db = s * w3 * b;
        }
    }
    // active set just right of left edge -> (a0,b0)
    bool act;
    if (k == 0) act = (a < 0.0f) || (a == 0.0f && b > 0.0f);
    else { float v = a * lo + b; act = (v > 0.0f) || (v == 0.0f && a > 0.0f); }
    float a0 = act ? w3 * a : 0.0f;
    float b0 = act ? w3 * b : 0.0f;
    for (int d = 32; d; d >>= 1) { a0 += __shfl_xor(a0, d); b0 += __shfl_xor(b0, d); }

    // stable rank sort of crossings (inf = invalid go last)
    int rank = 0;
    for (int l = 0; l < 64; ++l) {
        float o = __shfl(c, l);
        rank += (o < c) || (o == c && l < lane);
    }
    int src = 0;
    for (int l = 0; l < 64; ++l) {
        int rr = __shfl(rank, l);
        if (rr == lane) src = l;
    }
    float cs  = __shfl(c, src);
    float das = __shfl(da, src);
    float dbs = __shfl(db, src);
    for (int d = 1; d < 64; d <<= 1) {  // inclusive scan in sorted order
        float ta = __shfl_up(das, d);
        float tb = __shfl_up(dbs, d);
        if (lane >= d) { das += ta; dbs += tb; }
    }
    knots[k * ROW + lane] = cs;
    if (lane == 0) coef[k * ROW] = make_float2(a0, b0);
    coef[k * ROW + lane + 1] = make_float2(a0 + das, b0 + dbs);

    unsigned long long vm = __ballot(isfinite(c));
    if (lane == 0) nvalid[k] = (int)__popcll(vm);
}

// ---- k_pre_c: flatten (k,j) tables into one sorted knot array + grid (1 block) ----
__global__ __launch_bounds__(256) void k_pre_c(
    const float* __restrict__ bpg, float* __restrict__ knots,
    float2* __restrict__ coef, const int* __restrict__ nvalid,
    unsigned short* __restrict__ baseg)
{
    __shared__ float  T_s[TCAP];
    __shared__ float2 C_s[MMAX];
    __shared__ int off[66];
    const int tid = threadIdx.x;
    if (tid == 0) {
        int o = 0;
        for (int k = 0; k < 65; ++k) { off[k] = o; o += nvalid[k] + 1; }
        off[65] = o;  // = M + 1 coef entries; M = o - 1 knots
    }
    __syncthreads();
    const int M = off[65] - 1;

    for (int p = tid; p < 65 * ROW; p += 256) {
        int k = p / ROW, j = p - k * ROW;
        int nv = nvalid[k];
        int o = off[k];
        if (j < nv) T_s[o + j] = knots[k * ROW + j];
        else if (j == nv && k < 64) T_s[o + j] = bpg[k];
        if (j <= nv) C_s[o + j] = coef[k * ROW + j];
    }
    float2 lastC = coef[64 * ROW + nvalid[64]];
    __syncthreads();
    for (int i = M + tid; i < TCAP; i += 256) T_s[i] = INFINITY;     // knot sentinels
    for (int i = M + 1 + tid; i < MMAX; i += 256) C_s[i] = lastC;    // coef pad
    __syncthreads();

    for (int i = tid; i < TCAP; i += 256) knots[i] = T_s[i];
    for (int i = tid; i < MMAX; i += 256) coef[i] = C_s[i];
    for (int c = tid; c < NC; c += 256) {
        float left = GLO + c * DXF;
        int lo = 0, hi = M;  // lower bound: #{T <= left}
        while (lo < hi) { int mid = (lo + hi) >> 1; if (T_s[mid] <= left) lo = mid + 1; else hi = mid; }
        baseg[c] = (unsigned short)lo;
    }
}

// ---- k_eval: grid + branchless 12-window count, tables read via L1/L2 ----
// Tables total 59 KB (T 17K, C 34K, base 8K) -> cache-resident; no LDS staging
// keeps occupancy high (only ~1 KB LDS for segment aggregation).
__global__ __launch_bounds__(256) void k_eval(
    const float* __restrict__ x, const int* __restrict__ batch,
    const float* __restrict__ Tf, const float2* __restrict__ Cf,
    const unsigned short* __restrict__ baseg,
    unsigned long long* __restrict__ pooled, int* __restrict__ counts, int n)
{
    __shared__ unsigned long long aggP[CAP];
    __shared__ int aggC[CAP];
    __shared__ int segFirst_s;
    const int tid = threadIdx.x;
    if (tid < CAP) { aggP[tid] = 0ull; aggC[tid] = 0; }

    long long base = ((long long)blockIdx.x * 256 + tid) * PPT;
    const bool active = base < n;   // n % PPT == 0 -> active threads do full vectors

    float xs[PPT]; int ss[PPT];
    if (active) {
        const float4* xp = (const float4*)(x + base);
        const int4*   bp = (const int4*)(batch + base);
#pragma unroll
        for (int v = 0; v < PPT / 4; ++v) {
            float4 xv4 = xp[v]; int4 s4 = bp[v];
            xs[4 * v + 0] = xv4.x; xs[4 * v + 1] = xv4.y; xs[4 * v + 2] = xv4.z; xs[4 * v + 3] = xv4.w;
            ss[4 * v + 0] = s4.x;  ss[4 * v + 1] = s4.y;  ss[4 * v + 2] = s4.z;  ss[4 * v + 3] = s4.w;
        }
        if (tid == 0) segFirst_s = ss[0];
    }
    __syncthreads();
    const int segFirst = segFirst_s;

    if (active) {
        int curSeg = -1; long long acc = 0; int cnt = 0;
#pragma unroll
        for (int p = 0; p < PPT; ++p) {
            float xv = xs[p];
            int m;
            if (xv >= GLO) {
                int c = (int)((xv - GLO) * INVDX);
                c = c < NC - 1 ? c : NC - 1;
                if (c > 0 && GLO + c * DXF > xv) --c;  // fp rounding guard
                int b0i = baseg[c];
                int a0 = b0i & ~3;
                // 12-entry window from a0: entries below b0i are <= x by grid
                // construction, so m = a0 + count(T[a0..a0+11] <= x).
                const float4* tw = (const float4*)(Tf + a0);
                float4 t0 = tw[0], t1 = tw[1], t2 = tw[2];
                int cw = (t0.x <= xv) + (t0.y <= xv) + (t0.z <= xv) + (t0.w <= xv)
                       + (t1.x <= xv) + (t1.y <= xv) + (t1.z <= xv) + (t1.w <= xv)
                       + (t2.x <= xv) + (t2.y <= xv) + (t2.z <= xv) + (t2.w <= xv);
                m = a0 + cw;
                if (cw == 12) { while (Tf[m] <= xv) ++m; }  // ~never taken
            } else m = 0;
            float2 ab = Cf[m];
            float g = fmaf(ab.x, xv, ab.y);
            long long q = (long long)(g * SCALEF);  // exact: *2^30 is exponent shift
            int s = ss[p];
            if (s != curSeg) {
                if (cnt) {
                    int idx = curSeg - segFirst;
                    if (idx < CAP) {
                        atomicAdd(&aggP[idx], (unsigned long long)acc);
                        atomicAdd(&aggC[idx], cnt);
                    } else {
                        atomicAdd(&pooled[curSeg], (unsigned long long)acc);
                        atomicAdd(&counts[curSeg], cnt);
                    }
                }
                curSeg = s; acc = q; cnt = 1;
            } else { acc += q; ++cnt; }
        }
        if (cnt) {
            int idx = curSeg - segFirst;
            if (idx < CAP) {
                atomicAdd(&aggP[idx], (unsigned long long)acc);
                atomicAdd(&aggC[idx], cnt);
            } else {
                atomicAdd(&pooled[curSeg], (unsigned long long)acc);
                atomicAdd(&counts[curSeg], cnt);
            }
        }
    }
    __syncthreads();
    if (tid < CAP) {
        int c = aggC[tid];
        if (c) {
            atomicAdd(&pooled[segFirst + tid], aggP[tid]);
            atomicAdd(&counts[segFirst + tid], c);
        }
    }
}

// ---- k_out: weight recompute (on segment change) + broadcast to points ----
__global__ __launch_bounds__(256) void k_out(
    const int* __restrict__ batch,
    const unsigned long long* __restrict__ pooled, const int* __restrict__ counts,
    const float* __restrict__ b3, float* __restrict__ out, int n)
{
    long long base = ((long long)blockIdx.x * 256 + threadIdx.x) * PPT;
    if (base >= n) return;
    const float b3v = b3[0];
    const int4* bt = (const int4*)(batch + base);
    int4 b0 = bt[0], b1 = bt[1];
    int ss[PPT] = {b0.x, b0.y, b0.z, b0.w, b1.x, b1.y, b1.z, b1.w};

    float ov[PPT];
    int lastSeg = -1; float w = 0.0f;
#pragma unroll
    for (int p = 0; p < PPT; ++p) {
        int s = ss[p];
        if (s != lastSeg) {
            lastSeg = s;
            long long pv = (long long)pooled[s];   // L2-resident (16 KB)
            int cv = counts[s];
            double mean = ((double)pv / SCALE) / (double)(cv > 0 ? cv : 1);
            w = fmaxf((float)(mean + (double)b3v), 0.0f);
        }
        ov[p] = w;
    }
    float4* op = (float4*)(out + base);
    op[0] = make_float4(ov[0], ov[1], ov[2], ov[3]);
    op[1] = make_float4(ov[4], ov[5], ov[6], ov[7]);
}

extern "C" void kernel_launch(void* const* d_in, const int* in_sizes, int n_in,
                              void* d_out, int out_size, void* d_ws, size_t ws_size,
                              hipStream_t stream)
{
    const float* x   = (const float*)d_in[0];
    const int* batch = (const int*)d_in[1];
    const float* W1 = (const float*)d_in[2];
    const float* b1 = (const float*)d_in[3];
    const float* W2 = (const float*)d_in[4];
    const float* b2 = (const float*)d_in[5];
    const float* W3 = (const float*)d_in[6];
    const float* b3 = (const float*)d_in[7];
    float* out = (float*)d_out;
    const int n = in_sizes[0];

    char* ws = (char*)d_ws;
    unsigned long long* pooled = (unsigned long long*)ws;   // 16384
    int*    counts  = (int*)(ws + 16384);                   // 8192
    float*  bpg     = (float*)(ws + 24576);                 // 256
    int*    nvalid  = (int*)(ws + 24832);                   // 272
    float*  knots   = (float*)(ws + 25104);                 // 65*65 then flat T[TCAP]: 16960 (16B-aligned)
    float2* coef    = (float2*)(ws + 42064);                // 65*65 then flat C[MMAX]: 33808
    unsigned short* baseg = (unsigned short*)(ws + 75872);  // 8192 -> total ~84 KB

    k_pre_ab<<<65, 64, 0, stream>>>(W1, b1, W2, b2, W3, pooled, counts,
                                    bpg, knots, coef, nvalid);
    k_pre_c<<<1, 256, 0, stream>>>(bpg, knots, coef, nvalid, baseg);

    const int eblocks = (int)((n + 256LL * PPT - 1) / (256LL * PPT));
    k_eval<<<eblocks, 256, 0, stream>>>(x, batch, knots, coef, baseg, pooled, counts, n);
    k_out<<<eblocks, 256, 0, stream>>>(batch, pooled, counts, b3, out, n);
}

// Round 7
// 39.970 us; speedup vs baseline: 4.4968x; 1.4188x over previous
//
#include <hip/hip_runtime.h>
#include <math.h>

#define NSEG 2048
#define ROW 65
#define MMAX 4226          // max flat coef entries (M+1), M <= 64*65+64 = 4224
#define TCAP 4240          // flat knot array capacity incl window-read padding
#define NC 4096            // grid cells
#define GLO (-9.0f)
#define GHI (9.0f)
#define DXF ((GHI - GLO) / NC)
#define INVDX (NC / (GHI - GLO))
#define PPT 16
#define CAP 64             // per-block segment-aggregation slots
#define SCALEF 1073741824.0f  // 2^30 (exact exponent shift in fp32)
#define SCALE  1073741824.0

// ---- k_pre_ab: zero accumulators + per-interval crossing tables ----
// 65 blocks x 64 threads; each block redundantly sorts the 64 inner-relu
// breakpoints (cheap shfl rank-sort), then handles coarse interval k=blockIdx.
__global__ __launch_bounds__(64) void k_pre_ab(
    const float* __restrict__ W1, const float* __restrict__ b1,
    const float* __restrict__ W2, const float* __restrict__ b2,
    const float* __restrict__ W3,
    unsigned long long* __restrict__ pooled, int* __restrict__ counts,
    float* __restrict__ bpg, float* __restrict__ knots, float2* __restrict__ coef,
    int* __restrict__ nvalid)
{
    __shared__ float bps[64];
    __shared__ float w2s[64 * 65];   // padded: row stride 65 kills bank conflicts
    const int lane = threadIdx.x;
    const int k = blockIdx.x;

    // zero the global accumulators (spread across the 65 blocks)
    for (int i = k * 64 + lane; i < NSEG; i += 65 * 64) { pooled[i] = 0ull; counts[i] = 0; }

    // breakpoints: t_j = -b1/W1 (W1==0 -> sentinel), stable shfl rank-sort
    float w1l = W1[lane], b1l = b1[lane];
    float t = (w1l != 0.0f) ? (-b1l / w1l) : 3.0e38f;
    int r = 0;
    for (int l = 0; l < 64; ++l) {
        float o = __shfl(t, l);
        r += (o < t) || (o == t && l < lane);
    }
    bps[r] = t;

    // stage W2 into padded LDS (coalesced global reads)
    for (int i = lane; i < 4096; i += 64)
        w2s[(i >> 6) * 65 + (i & 63)] = W2[i];
    __syncthreads();
    if (k == 0) bpg[lane] = bps[lane];

    // affine coeffs of z_i (i = lane) on interval k: z = a*x + b
    float lof = (k == 0) ? (bps[0] - 1.0f) : bps[k - 1];
    float hif = (k == 64) ? (bps[63] + 1.0f) : bps[k];
    float xm = lof + 0.5f * (hif - lof);
    float a = 0.0f, b = b2[lane];
    for (int j = 0; j < 64; ++j) {
        float w1 = W1[j];
        if (w1 * xm + b1[j] > 0.0f) {
            float w2 = w2s[lane * 65 + j];
            a += w2 * w1;
            b += w2 * b1[j];
        }
    }

    // outer-relu crossing of z_i inside the open interval
    float w3 = W3[lane];
    float lo = (k == 0) ? -INFINITY : bps[k - 1];
    float hi = (k == 64) ? INFINITY : bps[k];
    float c = INFINITY, da = 0.0f, db = 0.0f;
    if (a != 0.0f) {
        float cc = -b / a;
        if (cc > lo && cc < hi) {
            float s = (a > 0.0f) ? 1.0f : -1.0f;
            c = cc; da = s * w3 * a; db = s * w3 * b;
        }
    }
    // active set just right of left edge -> (a0,b0)
    bool act;
    if (k == 0) act = (a < 0.0f) || (a == 0.0f && b > 0.0f);
    else { float v = a * lo + b; act = (v > 0.0f) || (v == 0.0f && a > 0.0f); }
    float a0 = act ? w3 * a : 0.0f;
    float b0 = act ? w3 * b : 0.0f;
    for (int d = 32; d; d >>= 1) { a0 += __shfl_xor(a0, d); b0 += __shfl_xor(b0, d); }

    // stable rank sort of crossings (inf = invalid go last)
    int rank = 0;
    for (int l = 0; l < 64; ++l) {
        float o = __shfl(c, l);
        rank += (o < c) || (o == c && l < lane);
    }
    int src = 0;
    for (int l = 0; l < 64; ++l) {
        int rr = __shfl(rank, l);
        if (rr == lane) src = l;
    }
    float cs  = __shfl(c, src);
    float das = __shfl(da, src);
    float dbs = __shfl(db, src);
    for (int d = 1; d < 64; d <<= 1) {  // inclusive scan in sorted order
        float ta = __shfl_up(das, d);
        float tb = __shfl_up(dbs, d);
        if (lane >= d) { das += ta; dbs += tb; }
    }
    knots[k * ROW + lane] = cs;
    if (lane == 0) coef[k * ROW] = make_float2(a0, b0);
    coef[k * ROW + lane + 1] = make_float2(a0 + das, b0 + dbs);

    unsigned long long vm = __ballot(isfinite(c));
    if (lane == 0) nvalid[k] = (int)__popcll(vm);
}

// ---- k_pre_c2: parallel flatten + grid fill (65 blocks x 64 threads) ----
// Block k: off[k] via wave scan of nvalid; writes its row slice of flat T/C;
// fills grid cells whose left edge lies in its coarse interval. Exactly one
// block writes each cell (per-cell ownership verify handles ties/sentinels).
__global__ __launch_bounds__(64) void k_pre_c2(
    const float* __restrict__ bpg, const int* __restrict__ nvalid,
    const float* __restrict__ knots2d, const float2* __restrict__ coef2d,
    float* __restrict__ Tf, float2* __restrict__ Cf,
    unsigned short* __restrict__ baseg)
{
    const int lane = threadIdx.x;
    const int k = blockIdx.x;
    __shared__ float bps[64];
    __shared__ float trow[64];

    bps[lane] = bpg[lane];
    trow[lane] = knots2d[k * ROW + lane];   // sorted fine knots, inf past nvalid

    // off[k] = sum_{k'<k} (nvalid[k']+1) via inclusive shfl scan over 64 lanes
    int v = nvalid[lane] + 1;
    int sc = v;
    for (int d = 1; d < 64; d <<= 1) {
        int tt = __shfl_up(sc, d);
        if (lane >= d) sc += tt;
    }
    const int offk  = (k == 0) ? 0 : __shfl(sc, k - 1);
    const int off64 = __shfl(sc, 63);
    const int nv    = nvalid[k];
    __syncthreads();

    // flat row slice: nv fine knots, then coarse bps[k] (k<64); coef j=0..nv
    for (int j = lane; j <= nv; j += 64) {
        if (j < nv) Tf[offk + j] = trow[j];
        else if (k < 64) Tf[offk + j] = bps[k];
        Cf[offk + j] = coef2d[k * ROW + j];
    }
    if (k == 64) {  // sentinels + coef pad beyond M
        const int M = off64 + nvalid[64];
        float2 lastC = coef2d[64 * ROW + nvalid[64]];
        for (int i = M + lane; i < TCAP; i += 64) Tf[i] = INFINITY;
        for (int i = M + 1 + lane; i < MMAX; i += 64) Cf[i] = lastC;
    }

    // grid cells owned by interval k: left in [bps[k-1], bps[k])
    float lob = (k == 0) ? GLO : bps[k - 1];
    float hib = (k == 64) ? GHI : bps[k];
    float clo = fminf(fmaxf((lob - GLO) * INVDX, 0.0f), (float)(NC - 1));
    float chi = fminf(fmaxf((hib - GLO) * INVDX, 0.0f), (float)(NC - 1));
    int c0 = max(0, (int)clo - 1);
    int c1 = min(NC - 1, (int)chi + 1);
    for (int c = c0 + lane; c <= c1; c += 64) {
        float left = GLO + c * DXF;
        bool ok = (k == 0 || left >= bps[k - 1]) && (k == 64 || left < bps[k]);
        if (ok) {
            int j = 0;  // #{fine knots <= left}; inf-padding makes 64-search safe
#pragma unroll
            for (int ofs = 32; ofs >= 1; ofs >>= 1)
                if (trow[j + ofs - 1] <= left) j += ofs;
            if (j < 64 && trow[j] <= left) ++j;
            baseg[c] = (unsigned short)(offk + j);
        }
    }
}

// ---- k_eval: grid + branchless 12-window count, tables read via L1/L2 ----
__global__ __launch_bounds__(256) void k_eval(
    const float* __restrict__ x, const int* __restrict__ batch,
    const float* __restrict__ Tf, const float2* __restrict__ Cf,
    const unsigned short* __restrict__ baseg,
    unsigned long long* __restrict__ pooled, int* __restrict__ counts, int n)
{
    __shared__ unsigned long long aggP[CAP];
    __shared__ int aggC[CAP];
    __shared__ int segFirst_s;
    const int tid = threadIdx.x;
    if (tid < CAP) { aggP[tid] = 0ull; aggC[tid] = 0; }

    long long base = ((long long)blockIdx.x * 256 + tid) * PPT;
    const bool active = base < n;   // n % PPT == 0 -> active threads do full vectors

    float xs[PPT]; int ss[PPT];
    if (active) {
        const float4* xp = (const float4*)(x + base);
        const int4*   bp = (const int4*)(batch + base);
#pragma unroll
        for (int v = 0; v < PPT / 4; ++v) {
            float4 xv4 = xp[v]; int4 s4 = bp[v];
            xs[4 * v + 0] = xv4.x; xs[4 * v + 1] = xv4.y; xs[4 * v + 2] = xv4.z; xs[4 * v + 3] = xv4.w;
            ss[4 * v + 0] = s4.x;  ss[4 * v + 1] = s4.y;  ss[4 * v + 2] = s4.z;  ss[4 * v + 3] = s4.w;
        }
        if (tid == 0) segFirst_s = ss[0];
    }
    __syncthreads();
    const int segFirst = segFirst_s;

    if (active) {
        int curSeg = -1; long long acc = 0; int cnt = 0;
#pragma unroll
        for (int p = 0; p < PPT; ++p) {
            float xv = xs[p];
            int m;
            if (xv >= GLO) {
                int c = (int)((xv - GLO) * INVDX);
                c = c < NC - 1 ? c : NC - 1;
                if (c > 0 && GLO + c * DXF > xv) --c;  // fp rounding guard
                int b0i = baseg[c];
                int a0 = b0i & ~3;
                // 12-entry window from a0: entries below b0i are <= x by grid
                // construction, so m = a0 + count(T[a0..a0+11] <= x).
                const float4* tw = (const float4*)(Tf + a0);
                float4 t0 = tw[0], t1 = tw[1], t2 = tw[2];
                int cw = (t0.x <= xv) + (t0.y <= xv) + (t0.z <= xv) + (t0.w <= xv)
                       + (t1.x <= xv) + (t1.y <= xv) + (t1.z <= xv) + (t1.w <= xv)
                       + (t2.x <= xv) + (t2.y <= xv) + (t2.z <= xv) + (t2.w <= xv);
                m = a0 + cw;
                if (cw == 12) { while (Tf[m] <= xv) ++m; }  // ~never taken
            } else m = 0;
            float2 ab = Cf[m];
            float g = fmaf(ab.x, xv, ab.y);
            long long q = (long long)(g * SCALEF);  // exact: *2^30 is exponent shift
            int s = ss[p];
            if (s != curSeg) {
                if (cnt) {
                    int idx = curSeg - segFirst;
                    if (idx < CAP) {
                        atomicAdd(&aggP[idx], (unsigned long long)acc);
                        atomicAdd(&aggC[idx], cnt);
                    } else {
                        atomicAdd(&pooled[curSeg], (unsigned long long)acc);
                        atomicAdd(&counts[curSeg], cnt);
                    }
                }
                curSeg = s; acc = q; cnt = 1;
            } else { acc += q; ++cnt; }
        }
        if (cnt) {
            int idx = curSeg - segFirst;
            if (idx < CAP) {
                atomicAdd(&aggP[idx], (unsigned long long)acc);
                atomicAdd(&aggC[idx], cnt);
            } else {
                atomicAdd(&pooled[curSeg], (unsigned long long)acc);
                atomicAdd(&counts[curSeg], cnt);
            }
        }
    }
    __syncthreads();
    if (tid < CAP) {
        int c = aggC[tid];
        if (c) {
            atomicAdd(&pooled[segFirst + tid], aggP[tid]);
            atomicAdd(&counts[segFirst + tid], c);
        }
    }
}

// ---- k_out: weight recompute (on segment change) + broadcast to points ----
__global__ __launch_bounds__(256) void k_out(
    const int* __restrict__ batch,
    const unsigned long long* __restrict__ pooled, const int* __restrict__ counts,
    const float* __restrict__ b3, float* __restrict__ out, int n)
{
    long long base = ((long long)blockIdx.x * 256 + threadIdx.x) * PPT;
    if (base >= n) return;
    const float b3v = b3[0];
    const int4* bt = (const int4*)(batch + base);
    int ss[PPT];
#pragma unroll
    for (int v = 0; v < PPT / 4; ++v) {
        int4 bb = bt[v];
        ss[4 * v + 0] = bb.x; ss[4 * v + 1] = bb.y; ss[4 * v + 2] = bb.z; ss[4 * v + 3] = bb.w;
    }

    float ov[PPT];
    int lastSeg = -1; float w = 0.0f;
#pragma unroll
    for (int p = 0; p < PPT; ++p) {
        int s = ss[p];
        if (s != lastSeg) {
            lastSeg = s;
            long long pv = (long long)pooled[s];   // L2-resident (16 KB)
            int cv = counts[s];
            double mean = ((double)pv / SCALE) / (double)(cv > 0 ? cv : 1);
            w = fmaxf((float)(mean + (double)b3v), 0.0f);
        }
        ov[p] = w;
    }
    float4* op = (float4*)(out + base);
#pragma unroll
    for (int v = 0; v < PPT / 4; ++v)
        op[v] = make_float4(ov[4 * v], ov[4 * v + 1], ov[4 * v + 2], ov[4 * v + 3]);
}

extern "C" void kernel_launch(void* const* d_in, const int* in_sizes, int n_in,
                              void* d_out, int out_size, void* d_ws, size_t ws_size,
                              hipStream_t stream)
{
    const float* x   = (const float*)d_in[0];
    const int* batch = (const int*)d_in[1];
    const float* W1 = (const float*)d_in[2];
    const float* b1 = (const float*)d_in[3];
    const float* W2 = (const float*)d_in[4];
    const float* b2 = (const float*)d_in[5];
    const float* W3 = (const float*)d_in[6];
    const float* b3 = (const float*)d_in[7];
    float* out = (float*)d_out;
    const int n = in_sizes[0];

    char* ws = (char*)d_ws;
    unsigned long long* pooled = (unsigned long long*)ws;   // 16384       -> 16384
    int*    counts   = (int*)(ws + 16384);                  //  8192       -> 24576
    float*  bpg      = (float*)(ws + 24576);                //   256       -> 24832
    int*    nvalid   = (int*)(ws + 24832);                  //   272       -> 25104
    float*  knots2d  = (float*)(ws + 25104);                // 16912       -> 42016
    float2* coef2d   = (float2*)(ws + 42016);               // 33808       -> 75824
    float*  Tflat    = (float*)(ws + 75824);                // 16960       -> 92784
    float2* Cflat    = (float2*)(ws + 92784);               // 33808       -> 126592
    unsigned short* baseg = (unsigned short*)(ws + 126592); //  8192       -> ~135 KB

    k_pre_ab<<<65, 64, 0, stream>>>(W1, b1, W2, b2, W3, pooled, counts,
                                    bpg, knots2d, coef2d, nvalid);
    k_pre_c2<<<65, 64, 0, stream>>>(bpg, nvalid, knots2d, coef2d,
                                    Tflat, Cflat, baseg);

    const int eblocks = (int)((n + 256LL * PPT - 1) / (256LL * PPT));
    k_eval<<<eblocks, 256, 0, stream>>>(x, batch, Tflat, Cflat, baseg, pooled, counts, n);
    k_out<<<eblocks, 256, 0, stream>>>(batch, pooled, counts, b3, out, n);
}

// Round 8
// 38.153 us; speedup vs baseline: 4.7109x; 1.0476x over previous
//
#include <hip/hip_runtime.h>
#include <math.h>

#define NSEG 2048
#define ROW 65
#define MMAX 4226          // max flat coef entries (M+1), M <= 64*65+64 = 4224
#define TCAP 4240          // flat knot array capacity incl window-read padding
#define NC 4096            // grid cells
#define GLO (-9.0f)
#define GHI (9.0f)
#define DXF ((GHI - GLO) / NC)
#define INVDX (NC / (GHI - GLO))
#define PPT_E 4            // eval: small PPT -> 1954 blocks, ~30 waves/CU (latency-bound)
#define PPT_O 8            // out: streaming, 977 blocks
#define CAP 64             // per-block segment-aggregation slots
#define SCALEF 1073741824.0f  // 2^30 (exact exponent shift in fp32)
#define SCALE  1073741824.0

// ---- k_pre_ab: zero accumulators + per-interval crossing tables ----
// 65 blocks x 64 threads; each block redundantly sorts the 64 inner-relu
// breakpoints (cheap shfl rank-sort), then handles coarse interval k=blockIdx.
__global__ __launch_bounds__(64) void k_pre_ab(
    const float* __restrict__ W1, const float* __restrict__ b1,
    const float* __restrict__ W2, const float* __restrict__ b2,
    const float* __restrict__ W3,
    unsigned long long* __restrict__ pooled, int* __restrict__ counts,
    float* __restrict__ bpg, float* __restrict__ knots, float2* __restrict__ coef,
    int* __restrict__ nvalid)
{
    __shared__ float bps[64];
    __shared__ float w2s[64 * 65];   // padded: row stride 65 kills bank conflicts
    const int lane = threadIdx.x;
    const int k = blockIdx.x;

    // zero the global accumulators (spread across the 65 blocks)
    for (int i = k * 64 + lane; i < NSEG; i += 65 * 64) { pooled[i] = 0ull; counts[i] = 0; }

    // breakpoints: t_j = -b1/W1 (W1==0 -> sentinel), stable shfl rank-sort
    float w1l = W1[lane], b1l = b1[lane];
    float t = (w1l != 0.0f) ? (-b1l / w1l) : 3.0e38f;
    int r = 0;
    for (int l = 0; l < 64; ++l) {
        float o = __shfl(t, l);
        r += (o < t) || (o == t && l < lane);
    }
    bps[r] = t;

    // stage W2 into padded LDS (coalesced global reads)
    for (int i = lane; i < 4096; i += 64)
        w2s[(i >> 6) * 65 + (i & 63)] = W2[i];
    __syncthreads();
    if (k == 0) bpg[lane] = bps[lane];

    // affine coeffs of z_i (i = lane) on interval k: z = a*x + b
    float lof = (k == 0) ? (bps[0] - 1.0f) : bps[k - 1];
    float hif = (k == 64) ? (bps[63] + 1.0f) : bps[k];
    float xm = lof + 0.5f * (hif - lof);
    float a = 0.0f, b = b2[lane];
    for (int j = 0; j < 64; ++j) {
        float w1 = W1[j];
        if (w1 * xm + b1[j] > 0.0f) {
            float w2 = w2s[lane * 65 + j];
            a += w2 * w1;
            b += w2 * b1[j];
        }
    }

    // outer-relu crossing of z_i inside the open interval
    float w3 = W3[lane];
    float lo = (k == 0) ? -INFINITY : bps[k - 1];
    float hi = (k == 64) ? INFINITY : bps[k];
    float c = INFINITY, da = 0.0f, db = 0.0f;
    if (a != 0.0f) {
        float cc = -b / a;
        if (cc > lo && cc < hi) {
            float s = (a > 0.0f) ? 1.0f : -1.0f;
            c = cc; da = s * w3 * a; db = s * w3 * b;
        }
    }
    // active set just right of left edge -> (a0,b0)
    bool act;
    if (k == 0) act = (a < 0.0f) || (a == 0.0f && b > 0.0f);
    else { float v = a * lo + b; act = (v > 0.0f) || (v == 0.0f && a > 0.0f); }
    float a0 = act ? w3 * a : 0.0f;
    float b0 = act ? w3 * b : 0.0f;
    for (int d = 32; d; d >>= 1) { a0 += __shfl_xor(a0, d); b0 += __shfl_xor(b0, d); }

    // stable rank sort of crossings (inf = invalid go last)
    int rank = 0;
    for (int l = 0; l < 64; ++l) {
        float o = __shfl(c, l);
        rank += (o < c) || (o == c && l < lane);
    }
    int src = 0;
    for (int l = 0; l < 64; ++l) {
        int rr = __shfl(rank, l);
        if (rr == lane) src = l;
    }
    float cs  = __shfl(c, src);
    float das = __shfl(da, src);
    float dbs = __shfl(db, src);
    for (int d = 1; d < 64; d <<= 1) {  // inclusive scan in sorted order
        float ta = __shfl_up(das, d);
        float tb = __shfl_up(dbs, d);
        if (lane >= d) { das += ta; dbs += tb; }
    }
    knots[k * ROW + lane] = cs;
    if (lane == 0) coef[k * ROW] = make_float2(a0, b0);
    coef[k * ROW + lane + 1] = make_float2(a0 + das, b0 + dbs);

    unsigned long long vm = __ballot(isfinite(c));
    if (lane == 0) nvalid[k] = (int)__popcll(vm);
}

// ---- k_pre_c2: parallel flatten + grid fill (65 blocks x 64 threads) ----
__global__ __launch_bounds__(64) void k_pre_c2(
    const float* __restrict__ bpg, const int* __restrict__ nvalid,
    const float* __restrict__ knots2d, const float2* __restrict__ coef2d,
    float* __restrict__ Tf, float2* __restrict__ Cf,
    unsigned short* __restrict__ baseg)
{
    const int lane = threadIdx.x;
    const int k = blockIdx.x;
    __shared__ float bps[64];
    __shared__ float trow[64];

    bps[lane] = bpg[lane];
    trow[lane] = knots2d[k * ROW + lane];   // sorted fine knots, inf past nvalid

    // off[k] = sum_{k'<k} (nvalid[k']+1) via inclusive shfl scan over 64 lanes
    int v = nvalid[lane] + 1;
    int sc = v;
    for (int d = 1; d < 64; d <<= 1) {
        int tt = __shfl_up(sc, d);
        if (lane >= d) sc += tt;
    }
    const int offk  = (k == 0) ? 0 : __shfl(sc, k - 1);
    const int off64 = __shfl(sc, 63);
    const int nv    = nvalid[k];
    __syncthreads();

    // flat row slice: nv fine knots, then coarse bps[k] (k<64); coef j=0..nv
    for (int j = lane; j <= nv; j += 64) {
        if (j < nv) Tf[offk + j] = trow[j];
        else if (k < 64) Tf[offk + j] = bps[k];
        Cf[offk + j] = coef2d[k * ROW + j];
    }
    if (k == 64) {  // sentinels + coef pad beyond M
        const int M = off64 + nvalid[64];
        float2 lastC = coef2d[64 * ROW + nvalid[64]];
        for (int i = M + lane; i < TCAP; i += 64) Tf[i] = INFINITY;
        for (int i = M + 1 + lane; i < MMAX; i += 64) Cf[i] = lastC;
    }

    // grid cells owned by interval k: left in [bps[k-1], bps[k])
    float lob = (k == 0) ? GLO : bps[k - 1];
    float hib = (k == 64) ? GHI : bps[k];
    float clo = fminf(fmaxf((lob - GLO) * INVDX, 0.0f), (float)(NC - 1));
    float chi = fminf(fmaxf((hib - GLO) * INVDX, 0.0f), (float)(NC - 1));
    int c0 = max(0, (int)clo - 1);
    int c1 = min(NC - 1, (int)chi + 1);
    for (int c = c0 + lane; c <= c1; c += 64) {
        float left = GLO + c * DXF;
        bool ok = (k == 0 || left >= bps[k - 1]) && (k == 64 || left < bps[k]);
        if (ok) {
            int j = 0;  // #{fine knots <= left}; inf-padding makes 64-search safe
#pragma unroll
            for (int ofs = 32; ofs >= 1; ofs >>= 1)
                if (trow[j + ofs - 1] <= left) j += ofs;
            if (j < 64 && trow[j] <= left) ++j;
            baseg[c] = (unsigned short)(offk + j);
        }
    }
}

// ---- k_eval: grid + branchless 12-window count, tables read via L1/L2 ----
// PPT=4 -> 1954 blocks (~30 waves/CU) to hide the dependent gather chain.
__global__ __launch_bounds__(256) void k_eval(
    const float* __restrict__ x, const int* __restrict__ batch,
    const float* __restrict__ Tf, const float2* __restrict__ Cf,
    const unsigned short* __restrict__ baseg,
    unsigned long long* __restrict__ pooled, int* __restrict__ counts, int n)
{
    __shared__ unsigned long long aggP[CAP];
    __shared__ int aggC[CAP];
    __shared__ int segFirst_s;
    const int tid = threadIdx.x;
    if (tid < CAP) { aggP[tid] = 0ull; aggC[tid] = 0; }

    long long base = ((long long)blockIdx.x * 256 + tid) * PPT_E;
    const bool active = base < n;   // n % PPT_E == 0 -> active threads do full vectors

    float xs[PPT_E]; int ss[PPT_E];
    if (active) {
        float4 xv4 = *(const float4*)(x + base);
        int4   s4  = *(const int4*)(batch + base);
        xs[0] = xv4.x; xs[1] = xv4.y; xs[2] = xv4.z; xs[3] = xv4.w;
        ss[0] = s4.x;  ss[1] = s4.y;  ss[2] = s4.z;  ss[3] = s4.w;
        if (tid == 0) segFirst_s = ss[0];
    }
    __syncthreads();
    const int segFirst = segFirst_s;

    if (active) {
        int curSeg = -1; long long acc = 0; int cnt = 0;
#pragma unroll
        for (int p = 0; p < PPT_E; ++p) {
            float xv = xs[p];
            int m;
            if (xv >= GLO) {
                int c = (int)((xv - GLO) * INVDX);
                c = c < NC - 1 ? c : NC - 1;
                if (c > 0 && GLO + c * DXF > xv) --c;  // fp rounding guard
                int b0i = baseg[c];
                int a0 = b0i & ~3;
                // 12-entry window from a0: entries below b0i are <= x by grid
                // construction, so m = a0 + count(T[a0..a0+11] <= x).
                const float4* tw = (const float4*)(Tf + a0);
                float4 t0 = tw[0], t1 = tw[1], t2 = tw[2];
                int cw = (t0.x <= xv) + (t0.y <= xv) + (t0.z <= xv) + (t0.w <= xv)
                       + (t1.x <= xv) + (t1.y <= xv) + (t1.z <= xv) + (t1.w <= xv)
                       + (t2.x <= xv) + (t2.y <= xv) + (t2.z <= xv) + (t2.w <= xv);
                m = a0 + cw;
                if (cw == 12) { while (Tf[m] <= xv) ++m; }  // ~never taken
            } else m = 0;
            float2 ab = Cf[m];
            float g = fmaf(ab.x, xv, ab.y);
            long long q = (long long)(g * SCALEF);  // exact: *2^30 is exponent shift
            int s = ss[p];
            if (s != curSeg) {
                if (cnt) {
                    int idx = curSeg - segFirst;
                    if (idx < CAP) {
                        atomicAdd(&aggP[idx], (unsigned long long)acc);
                        atomicAdd(&aggC[idx], cnt);
                    } else {
                        atomicAdd(&pooled[curSeg], (unsigned long long)acc);
                        atomicAdd(&counts[curSeg], cnt);
                    }
                }
                curSeg = s; acc = q; cnt = 1;
            } else { acc += q; ++cnt; }
        }
        if (cnt) {
            int idx = curSeg - segFirst;
            if (idx < CAP) {
                atomicAdd(&aggP[idx], (unsigned long long)acc);
                atomicAdd(&aggC[idx], cnt);
            } else {
                atomicAdd(&pooled[curSeg], (unsigned long long)acc);
                atomicAdd(&counts[curSeg], cnt);
            }
        }
    }
    __syncthreads();
    if (tid < CAP) {
        int c = aggC[tid];
        if (c) {
            atomicAdd(&pooled[segFirst + tid], aggP[tid]);
            atomicAdd(&counts[segFirst + tid], c);
        }
    }
}

// ---- k_out: weight recompute (on segment change) + broadcast to points ----
__global__ __launch_bounds__(256) void k_out(
    const int* __restrict__ batch,
    const unsigned long long* __restrict__ pooled, const int* __restrict__ counts,
    const float* __restrict__ b3, float* __restrict__ out, int n)
{
    long long base = ((long long)blockIdx.x * 256 + threadIdx.x) * PPT_O;
    if (base >= n) return;
    const float b3v = b3[0];
    const int4* bt = (const int4*)(batch + base);
    int ss[PPT_O];
#pragma unroll
    for (int v = 0; v < PPT_O / 4; ++v) {
        int4 bb = bt[v];
        ss[4 * v + 0] = bb.x; ss[4 * v + 1] = bb.y; ss[4 * v + 2] = bb.z; ss[4 * v + 3] = bb.w;
    }

    float ov[PPT_O];
    int lastSeg = -1; float w = 0.0f;
#pragma unroll
    for (int p = 0; p < PPT_O; ++p) {
        int s = ss[p];
        if (s != lastSeg) {
            lastSeg = s;
            long long pv = (long long)pooled[s];   // L2-resident (16 KB)
            int cv = counts[s];
            double mean = ((double)pv / SCALE) / (double)(cv > 0 ? cv : 1);
            w = fmaxf((float)(mean + (double)b3v), 0.0f);
        }
        ov[p] = w;
    }
    float4* op = (float4*)(out + base);
#pragma unroll
    for (int v = 0; v < PPT_O / 4; ++v)
        op[v] = make_float4(ov[4 * v], ov[4 * v + 1], ov[4 * v + 2], ov[4 * v + 3]);
}

extern "C" void kernel_launch(void* const* d_in, const int* in_sizes, int n_in,
                              void* d_out, int out_size, void* d_ws, size_t ws_size,
                              hipStream_t stream)
{
    const float* x   = (const float*)d_in[0];
    const int* batch = (const int*)d_in[1];
    const float* W1 = (const float*)d_in[2];
    const float* b1 = (const float*)d_in[3];
    const float* W2 = (const float*)d_in[4];
    const float* b2 = (const float*)d_in[5];
    const float* W3 = (const float*)d_in[6];
    const float* b3 = (const float*)d_in[7];
    float* out = (float*)d_out;
    const int n = in_sizes[0];

    char* ws = (char*)d_ws;
    unsigned long long* pooled = (unsigned long long*)ws;   // 16384       -> 16384
    int*    counts   = (int*)(ws + 16384);                  //  8192       -> 24576
    float*  bpg      = (float*)(ws + 24576);                //   256       -> 24832
    int*    nvalid   = (int*)(ws + 24832);                  //   272       -> 25104
    float*  knots2d  = (float*)(ws + 25104);                // 16912       -> 42016
    float2* coef2d   = (float2*)(ws + 42016);               // 33808       -> 75824
    float*  Tflat    = (float*)(ws + 75824);                // 16960       -> 92784
    float2* Cflat    = (float2*)(ws + 92784);               // 33808       -> 126592
    unsigned short* baseg = (unsigned short*)(ws + 126592); //  8192       -> ~135 KB

    k_pre_ab<<<65, 64, 0, stream>>>(W1, b1, W2, b2, W3, pooled, counts,
                                    bpg, knots2d, coef2d, nvalid);
    k_pre_c2<<<65, 64, 0, stream>>>(bpg, nvalid, knots2d, coef2d,
                                    Tflat, Cflat, baseg);

    const int eblocks = (int)((n + 256LL * PPT_E - 1) / (256LL * PPT_E));
    k_eval<<<eblocks, 256, 0, stream>>>(x, batch, Tflat, Cflat, baseg, pooled, counts, n);
    const int oblocks = (int)((n + 256LL * PPT_O - 1) / (256LL * PPT_O));
    k_out<<<oblocks, 256, 0, stream>>>(batch, pooled, counts, b3, out, n);
}

// Round 9
// 35.389 us; speedup vs baseline: 5.0789x; 1.0781x over previous
//
#include <hip/hip_runtime.h>
#include <math.h>

#define NSEG 2048
#define ROW 65
#define MMAX 4226          // max flat coef entries (M+1), M <= 64*65+64 = 4224
#define TCAP 4240          // flat knot array capacity incl window-read padding
#define NC 4096            // grid cells
#define GLO (-9.0f)
#define GHI (9.0f)
#define DXF ((GHI - GLO) / NC)
#define INVDX (NC / (GHI - GLO))
#define PPT_E 4            // eval: 1954 blocks, ~30 waves/CU (latency-bound)
#define CAP 64             // per-block segment-aggregation slots
#define SCALEF 1073741824.0f  // 2^30 (exact exponent shift in fp32)
#define SCALE  1073741824.0

// ---- k_pre_ab: zero accumulators + per-interval crossing tables ----
__global__ __launch_bounds__(64) void k_pre_ab(
    const float* __restrict__ W1, const float* __restrict__ b1,
    const float* __restrict__ W2, const float* __restrict__ b2,
    const float* __restrict__ W3,
    unsigned long long* __restrict__ pooled, int* __restrict__ counts,
    float* __restrict__ bpg, float* __restrict__ knots, float2* __restrict__ coef,
    int* __restrict__ nvalid)
{
    __shared__ float bps[64];
    __shared__ float w2s[64 * 65];   // padded: row stride 65 kills bank conflicts
    __shared__ float sc_[64], sda[64], sdb[64];
    const int lane = threadIdx.x;
    const int k = blockIdx.x;

    // zero the global accumulators (spread across the 65 blocks)
    for (int i = k * 64 + lane; i < NSEG; i += 65 * 64) { pooled[i] = 0ull; counts[i] = 0; }

    // breakpoints: t_j = -b1/W1 (W1==0 -> sentinel), stable shfl rank-sort
    float w1l = W1[lane], b1l = b1[lane];
    float t = (w1l != 0.0f) ? (-b1l / w1l) : 3.0e38f;
    int r = 0;
    for (int l = 0; l < 64; ++l) {
        float o = __shfl(t, l);
        r += (o < t) || (o == t && l < lane);
    }
    bps[r] = t;

    // stage W2 into padded LDS (coalesced global reads)
    for (int i = lane; i < 4096; i += 64)
        w2s[(i >> 6) * 65 + (i & 63)] = W2[i];
    __syncthreads();
    if (k == 0) bpg[lane] = bps[lane];

    // affine coeffs of z_i (i = lane) on interval k: z = a*x + b
    float lof = (k == 0) ? (bps[0] - 1.0f) : bps[k - 1];
    float hif = (k == 64) ? (bps[63] + 1.0f) : bps[k];
    float xm = lof + 0.5f * (hif - lof);
    float a = 0.0f, b = b2[lane];
    for (int j = 0; j < 64; ++j) {
        float w1 = W1[j];
        if (w1 * xm + b1[j] > 0.0f) {
            float w2 = w2s[lane * 65 + j];
            a += w2 * w1;
            b += w2 * b1[j];
        }
    }

    // outer-relu crossing of z_i inside the open interval
    float w3 = W3[lane];
    float lo = (k == 0) ? -INFINITY : bps[k - 1];
    float hi = (k == 64) ? INFINITY : bps[k];
    float c = INFINITY, da = 0.0f, db = 0.0f;
    if (a != 0.0f) {
        float cc = -b / a;
        if (cc > lo && cc < hi) {
            float s = (a > 0.0f) ? 1.0f : -1.0f;
            c = cc; da = s * w3 * a; db = s * w3 * b;
        }
    }
    // active set just right of left edge -> (a0,b0)
    bool act;
    if (k == 0) act = (a < 0.0f) || (a == 0.0f && b > 0.0f);
    else { float v = a * lo + b; act = (v > 0.0f) || (v == 0.0f && a > 0.0f); }
    float a0 = act ? w3 * a : 0.0f;
    float b0 = act ? w3 * b : 0.0f;
    for (int d = 32; d; d >>= 1) { a0 += __shfl_xor(a0, d); b0 += __shfl_xor(b0, d); }

    // stable rank sort of crossings (inf = invalid go last); scatter via LDS
    int rank = 0;
    for (int l = 0; l < 64; ++l) {
        float o = __shfl(c, l);
        rank += (o < c) || (o == c && l < lane);
    }
    sc_[rank] = c; sda[rank] = da; sdb[rank] = db;
    __syncthreads();
    float cs = sc_[lane], das = sda[lane], dbs = sdb[lane];
    for (int d = 1; d < 64; d <<= 1) {  // inclusive scan in sorted order
        float ta = __shfl_up(das, d);
        float tb = __shfl_up(dbs, d);
        if (lane >= d) { das += ta; dbs += tb; }
    }
    knots[k * ROW + lane] = cs;
    if (lane == 0) coef[k * ROW] = make_float2(a0, b0);
    coef[k * ROW + lane + 1] = make_float2(a0 + das, b0 + dbs);

    unsigned long long vm = __ballot(isfinite(cs));
    if (lane == 0) nvalid[k] = (int)__popcll(vm);
}

// ---- k_pre_c2: parallel flatten + grid fill (65 blocks x 64 threads) ----
__global__ __launch_bounds__(64) void k_pre_c2(
    const float* __restrict__ bpg, const int* __restrict__ nvalid,
    const float* __restrict__ knots2d, const float2* __restrict__ coef2d,
    float* __restrict__ Tf, float2* __restrict__ Cf,
    unsigned short* __restrict__ baseg, int* __restrict__ Mg)
{
    const int lane = threadIdx.x;
    const int k = blockIdx.x;
    __shared__ float bps[64];
    __shared__ float trow[64];

    bps[lane] = bpg[lane];
    trow[lane] = knots2d[k * ROW + lane];   // sorted fine knots, inf past nvalid

    // off[k] = sum_{k'<k} (nvalid[k']+1) via inclusive shfl scan over 64 lanes
    int v = nvalid[lane] + 1;
    int sc = v;
    for (int d = 1; d < 64; d <<= 1) {
        int tt = __shfl_up(sc, d);
        if (lane >= d) sc += tt;
    }
    const int offk  = (k == 0) ? 0 : __shfl(sc, k - 1);
    const int off64 = __shfl(sc, 63);
    const int nv    = nvalid[k];
    __syncthreads();

    // flat row slice: nv fine knots, then coarse bps[k] (k<64); coef j=0..nv
    for (int j = lane; j <= nv; j += 64) {
        if (j < nv) Tf[offk + j] = trow[j];
        else if (k < 64) Tf[offk + j] = bps[k];
        Cf[offk + j] = coef2d[k * ROW + j];
    }
    if (k == 64) {  // sentinels + coef pad beyond M; publish M
        const int M = off64 + nvalid[64];
        float2 lastC = coef2d[64 * ROW + nvalid[64]];
        for (int i = M + lane; i < TCAP; i += 64) Tf[i] = INFINITY;
        for (int i = M + 1 + lane; i < MMAX; i += 64) Cf[i] = lastC;
        if (lane == 0) Mg[0] = M;
    }

    // grid cells owned by interval k: left in [bps[k-1], bps[k])
    float lob = (k == 0) ? GLO : bps[k - 1];
    float hib = (k == 64) ? GHI : bps[k];
    float clo = fminf(fmaxf((lob - GLO) * INVDX, 0.0f), (float)(NC - 1));
    float chi = fminf(fmaxf((hib - GLO) * INVDX, 0.0f), (float)(NC - 1));
    int c0 = max(0, (int)clo - 1);
    int c1 = min(NC - 1, (int)chi + 1);
    for (int c = c0 + lane; c <= c1; c += 64) {
        float left = GLO + c * DXF;
        bool ok = (k == 0 || left >= bps[k - 1]) && (k == 64 || left < bps[k]);
        if (ok) {
            int j = 0;  // #{fine knots <= left}; inf-padding makes 64-search safe
#pragma unroll
            for (int ofs = 32; ofs >= 1; ofs >>= 1)
                if (trow[j + ofs - 1] <= left) j += ofs;
            if (j < 64 && trow[j] <= left) ++j;
            baseg[c] = (unsigned short)(offk + j);
        }
    }
}

// ---- k_eval: LDS-staged knot window + segment pooling + boundary detection ----
__global__ __launch_bounds__(256) void k_eval(
    const float* __restrict__ x, const int* __restrict__ batch,
    const float* __restrict__ Tf, const float2* __restrict__ Cf,
    const unsigned short* __restrict__ baseg, const int* __restrict__ Mg,
    unsigned long long* __restrict__ pooled, int* __restrict__ counts,
    int* __restrict__ seg_start, int n)
{
    __shared__ __align__(16) float T_s[TCAP];
    __shared__ unsigned long long aggP[CAP];
    __shared__ int aggC[CAP];
    __shared__ int segFirst_s;
    const int tid = threadIdx.x;

    // stage only the live part of the knot table (M ~ a few hundred expected)
    const int stageN = min(TCAP, (Mg[0] + 32) & ~15);
    for (int i = tid; i < (stageN >> 2); i += 256)
        ((float4*)T_s)[i] = ((const float4*)Tf)[i];
    if (tid < CAP) { aggP[tid] = 0ull; aggC[tid] = 0; }

    long long base = ((long long)blockIdx.x * 256 + tid) * PPT_E;
    const bool active = base < n;   // n % PPT_E == 0 -> active threads do full vectors

    float xs[PPT_E]; int ss[PPT_E];
    if (active) {
        float4 xv4 = *(const float4*)(x + base);
        int4   s4  = *(const int4*)(batch + base);
        xs[0] = xv4.x; xs[1] = xv4.y; xs[2] = xv4.z; xs[3] = xv4.w;
        ss[0] = s4.x;  ss[1] = s4.y;  ss[2] = s4.z;  ss[3] = s4.w;
        if (tid == 0) segFirst_s = ss[0];
        // segment-boundary detection (sorted batch): first point of each segment
        int prev = (base > 0) ? batch[base - 1] : -1;
        if (ss[0] != prev) seg_start[ss[0]] = (int)base;
#pragma unroll
        for (int p = 1; p < PPT_E; ++p)
            if (ss[p] != ss[p - 1]) seg_start[ss[p]] = (int)(base + p);
    }
    __syncthreads();
    const int segFirst = segFirst_s;

    if (active) {
        int curSeg = -1; long long acc = 0; int cnt = 0;
#pragma unroll
        for (int p = 0; p < PPT_E; ++p) {
            float xv = xs[p];
            int m;
            if (xv >= GLO) {
                int c = (int)((xv - GLO) * INVDX);
                c = c < NC - 1 ? c : NC - 1;
                if (c > 0 && GLO + c * DXF > xv) --c;  // fp rounding guard
                int b0i = baseg[c];
                int a0 = b0i & ~3;
                // 12-entry LDS window from a0: entries below b0i are <= x by
                // grid construction, so m = a0 + count(T[a0..a0+11] <= x).
                const float4* tw = (const float4*)(T_s + a0);
                float4 t0 = tw[0], t1 = tw[1], t2 = tw[2];
                int cw = (t0.x <= xv) + (t0.y <= xv) + (t0.z <= xv) + (t0.w <= xv)
                       + (t1.x <= xv) + (t1.y <= xv) + (t1.z <= xv) + (t1.w <= xv)
                       + (t2.x <= xv) + (t2.y <= xv) + (t2.z <= xv) + (t2.w <= xv);
                m = a0 + cw;
                if (cw == 12) { while (T_s[m] <= xv) ++m; }  // ~never taken
            } else m = 0;
            float2 ab = Cf[m];
            float g = fmaf(ab.x, xv, ab.y);
            long long q = (long long)(g * SCALEF);  // exact: *2^30 is exponent shift
            int s = ss[p];
            if (s != curSeg) {
                if (cnt) {
                    int idx = curSeg - segFirst;
                    if (idx < CAP) {
                        atomicAdd(&aggP[idx], (unsigned long long)acc);
                        atomicAdd(&aggC[idx], cnt);
                    } else {
                        atomicAdd(&pooled[curSeg], (unsigned long long)acc);
                        atomicAdd(&counts[curSeg], cnt);
                    }
                }
                curSeg = s; acc = q; cnt = 1;
            } else { acc += q; ++cnt; }
        }
        if (cnt) {
            int idx = curSeg - segFirst;
            if (idx < CAP) {
                atomicAdd(&aggP[idx], (unsigned long long)acc);
                atomicAdd(&aggC[idx], cnt);
            } else {
                atomicAdd(&pooled[curSeg], (unsigned long long)acc);
                atomicAdd(&counts[curSeg], cnt);
            }
        }
    }
    __syncthreads();
    if (tid < CAP) {
        int c = aggC[tid];
        if (c) {
            atomicAdd(&pooled[segFirst + tid], aggP[tid]);
            atomicAdd(&counts[segFirst + tid], c);
        }
    }
}

// ---- k_out: one block per segment, write the constant weight run ----
__global__ __launch_bounds__(128) void k_out(
    const unsigned long long* __restrict__ pooled, const int* __restrict__ counts,
    const int* __restrict__ seg_start, const float* __restrict__ b3,
    float* __restrict__ out)
{
    const int s = blockIdx.x;
    const int cnt = counts[s];
    if (cnt == 0) return;
    const int start = seg_start[s];

    long long pv = (long long)pooled[s];
    double mean = ((double)pv / SCALE) / (double)cnt;
    float w = fmaxf((float)(mean + (double)b3[0]), 0.0f);

    const int tid = threadIdx.x;
    int a = (start + 3) & ~3;               // align to float4
    int head = min(a - start, cnt);
    if (tid < head) out[start + tid] = w;
    int rem = cnt - head;
    if (rem <= 0) return;
    int nvec = rem >> 2;
    float4 wv = make_float4(w, w, w, w);
    float4* o4 = (float4*)(out + start + head);
    for (int i = tid; i < nvec; i += 128) o4[i] = wv;
    int tail = rem & 3;
    if (tid < tail) out[start + head + (nvec << 2) + tid] = w;
}

extern "C" void kernel_launch(void* const* d_in, const int* in_sizes, int n_in,
                              void* d_out, int out_size, void* d_ws, size_t ws_size,
                              hipStream_t stream)
{
    const float* x   = (const float*)d_in[0];
    const int* batch = (const int*)d_in[1];
    const float* W1 = (const float*)d_in[2];
    const float* b1 = (const float*)d_in[3];
    const float* W2 = (const float*)d_in[4];
    const float* b2 = (const float*)d_in[5];
    const float* W3 = (const float*)d_in[6];
    const float* b3 = (const float*)d_in[7];
    float* out = (float*)d_out;
    const int n = in_sizes[0];

    char* ws = (char*)d_ws;
    unsigned long long* pooled = (unsigned long long*)ws;   // 16384  -> 16384
    int*    counts   = (int*)(ws + 16384);                  //  8192  -> 24576
    float*  bpg      = (float*)(ws + 24576);                //   256  -> 24832
    int*    nvalid   = (int*)(ws + 24832);                  //   272  -> 25104
    int*    Mg       = (int*)(ws + 25104);                  //    16  -> 25120
    int*    seg_start= (int*)(ws + 25120);                  //  8192  -> 33312
    float*  knots2d  = (float*)(ws + 33312);                // 16912  -> 50224
    float2* coef2d   = (float2*)(ws + 50224);               // 33808  -> 84032
    float*  Tflat    = (float*)(ws + 84032);                // 16960  -> 100992
    float2* Cflat    = (float2*)(ws + 100992);              // 33808  -> 134800
    unsigned short* baseg = (unsigned short*)(ws + 134800); //  8192  -> ~143 KB

    k_pre_ab<<<65, 64, 0, stream>>>(W1, b1, W2, b2, W3, pooled, counts,
                                    bpg, knots2d, coef2d, nvalid);
    k_pre_c2<<<65, 64, 0, stream>>>(bpg, nvalid, knots2d, coef2d,
                                    Tflat, Cflat, baseg, Mg);

    const int eblocks = (int)((n + 256LL * PPT_E - 1) / (256LL * PPT_E));
    k_eval<<<eblocks, 256, 0, stream>>>(x, batch, Tflat, Cflat, baseg, Mg,
                                        pooled, counts, seg_start, n);
    k_out<<<NSEG, 128, 0, stream>>>(pooled, counts, seg_start, b3, out);
}